// Round 9
// baseline (154.177 us; speedup 1.0000x reference)
//
#include <hip/hip_runtime.h>

// Problem: D=512, H=8, L=4, NE=8, B=32, S=512. fp32 in / fp32 out.
//
// Reduction chain (R3-verified absmax 0.0):
//   cross-attn Sk=1 -> softmax==1 -> last[b] = (ctx[b]@cWv+cbv)@cWo+cbo,
//   ctx[b] = c0[b]*ctxW[0]+c1[b]*ctxW[1]+ctxb -> batch factors out:
//     A_i = x_i@cWv (+cbv), B_i = A_i@cWo (+cbo), P_i = B_i@spW[s,h] (+spb),
//     out[b,h,o] = c0[b]*P0 + c1[b]*P1 + P2  (s=sid[b])
//
// Cost model (R3-R8): harness floor ~125us; each graph level ~7-9us; sync
// alternatives lose (coop +70 R5, flags +5 R6, redundant compute = per-CU
// BW trap R7). R9: depth 3 -> 2. K1 fuses A+B sync-free: block k owns d-slice
// [16k,16k+16): computes A_i[slice] then partial_i[c] = sum_{d in slice}
// A_i[d]*cWo[d][c] for ALL c, writes 1536-float partial. K2 reduces the 32
// partials (L2-hot) and does heads. Zero redundancy, zero cross-block sync.

#define DD 512

// K1: grid 32 x 512 thr. Block k owns d-slice [16k, 16k+16).
__global__ __launch_bounds__(512) void stage_AB(
    const float* __restrict__ ctxW,   // (2,512)
    const float* __restrict__ ctxb,   // (512)
    const float* __restrict__ cWv,    // (512,512)
    const float* __restrict__ cbv,    // (512)
    const float* __restrict__ cWo,    // (512,512)
    float*       __restrict__ wsP)    // (32,3,512) partials
{
    __shared__ float sx[3 * DD];
    __shared__ float red[32][48];     // [egroup][d16*3+vec]
    __shared__ float st[48];          // A slice: [d16*3+vec]
    const int t = threadIdx.x;
    const int dbase = blockIdx.x * 16;
    const int d16 = t & 15, eg = t >> 4;   // 16 d x 32 e-groups of 16

    // ---- preloads (independent; all 32+16 loads in flight early) ----
    const float* vp = cWv + (size_t)(eg * 16) * DD + dbase + d16;
    float wv[16];
    #pragma unroll
    for (int j = 0; j < 16; ++j) wv[j] = vp[(size_t)j * DD];
    const float* op = cWo + (size_t)dbase * DD + t;   // rows dbase..+15, col t
    float wo[16];
    #pragma unroll
    for (int j = 0; j < 16; ++j) wo[j] = op[(size_t)j * DD];

    if (t < DD) {
        sx[t]          = ctxW[t];
        sx[DD + t]     = ctxW[DD + t];
        sx[2 * DD + t] = ctxb[t];
    }
    __syncthreads();

    // ---- step 1: A_i[dbase+d16] partial over e-group ----
    {
        float p0 = 0.f, p1 = 0.f, p2 = 0.f;
        #pragma unroll
        for (int j = 0; j < 16; ++j) {
            const int e = eg * 16 + j;
            p0 += sx[e] * wv[j];
            p1 += sx[DD + e] * wv[j];
            p2 += sx[2 * DD + e] * wv[j];
        }
        red[eg][d16 * 3 + 0] = p0;
        red[eg][d16 * 3 + 1] = p1;
        red[eg][d16 * 3 + 2] = p2;
    }
    __syncthreads();
    if (t < 48) {                         // reduce 32 e-groups; + cbv
        const int dd = t / 3, vec = t % 3;
        float s = 0.f;
        #pragma unroll
        for (int g = 0; g < 32; ++g) s += red[g][t];
        if (vec == 2) s += cbv[dbase + dd];
        st[t] = s;
    }
    __syncthreads();

    // ---- step 2: partial_i[c] = sum_{j<16} A_i[dbase+j] * cWo[dbase+j][c],
    //      thread owns c = t (coalesced 2KB rows, preloaded) ----
    {
        float q0 = 0.f, q1 = 0.f, q2 = 0.f;
        #pragma unroll
        for (int j = 0; j < 16; ++j) {
            const float w = wo[j];        // st reads are wave-uniform -> bcast
            q0 += st[j * 3 + 0] * w;
            q1 += st[j * 3 + 1] * w;
            q2 += st[j * 3 + 2] * w;
        }
        float* dst = wsP + (size_t)blockIdx.x * 1536;
        dst[t]          = q0;
        dst[DD + t]     = q1;
        dst[2 * DD + t] = q2;
    }
}

// K2: heads + partial reduction + batch broadcast.
// grid 64 (s=blk&7, h=(blk>>3)&1, q=blk>>4) x 256 thr.
__global__ __launch_bounds__(256) void stage_heads(
    const float* __restrict__ wsP,    // (32,3,512)
    const float* __restrict__ cbo,    // (512)
    const float* __restrict__ spWp, const float* __restrict__ spbp,
    const float* __restrict__ spWa, const float* __restrict__ spba,
    const float* __restrict__ ctxin,  // (32,2)
    const int*   __restrict__ sid,    // (32)
    float*       __restrict__ out)    // pred (32,64) then act (32,64)
{
    __shared__ float sb[3 * DD];
    __shared__ float red[16][48];
    __shared__ float pv[48];
    __shared__ float sc0[32], sc1[32];
    __shared__ int   ssid[32];
    const int t = threadIdx.x;
    const int s = blockIdx.x & 7, h = (blockIdx.x >> 3) & 1, q = blockIdx.x >> 4;

    // preload head weights first (32 independent loads)
    const float* W    = (h ? spWa : spWp) + (size_t)s * DD * 64;
    const float* bias = (h ? spba : spbp) + s * 64;
    const int o16 = t & 15, dg = t >> 4;
    const float* wp = W + (size_t)(dg * 32) * 64 + q * 16 + o16;
    float wreg[32];
    #pragma unroll
    for (int j = 0; j < 32; ++j) wreg[j] = wp[(size_t)j * 64];

    if (t < 32) {
        ssid[t] = sid[t];
        sc0[t] = ctxin[2 * t];
        sc1[t] = ctxin[2 * t + 1];
    }

    // reduce the 32 partials into B (L2-hot, coalesced per k)
    #pragma unroll
    for (int r = 0; r < 6; ++r) {
        const int j = t + 256 * r;
        float v = 0.f;
        #pragma unroll
        for (int k = 0; k < 32; ++k) v += wsP[(size_t)k * 1536 + j];
        if (j >= 2 * DD) v += cbo[j - 2 * DD];
        sb[j] = v;
    }
    __syncthreads();

    // head GEMV: 16 outs x 16 d-groups of 32
    {
        float p0 = 0.f, p1 = 0.f, p2 = 0.f;
        #pragma unroll
        for (int j = 0; j < 32; ++j) {
            const int d = dg * 32 + j;
            p0 += sb[d] * wreg[j];
            p1 += sb[DD + d] * wreg[j];
            p2 += sb[2 * DD + d] * wreg[j];
        }
        red[dg][o16 * 3 + 0] = p0;
        red[dg][o16 * 3 + 1] = p1;
        red[dg][o16 * 3 + 2] = p2;
    }
    __syncthreads();

    if (t < 48) {
        const int oo = t / 3, vec = t % 3;
        float a = 0.f;
        #pragma unroll
        for (int g = 0; g < 16; ++g) a += red[g][t];
        if (vec == 2) a += bias[q * 16 + oo];
        pv[oo * 3 + vec] = a;
    }
    __syncthreads();

    if (t < 16) {
        const float v0 = pv[t * 3], v1 = pv[t * 3 + 1], v2 = pv[t * 3 + 2];
        #pragma unroll
        for (int b = 0; b < 32; ++b) {
            if (ssid[b] == s) {           // wave-uniform
                out[h * 2048 + b * 64 + q * 16 + t] =
                    sc0[b] * v0 + sc1[b] * v1 + v2;
            }
        }
    }
}

extern "C" void kernel_launch(void* const* d_in, const int* in_sizes, int n_in,
                              void* d_out, int out_size, void* d_ws, size_t ws_size,
                              hipStream_t stream) {
    // 0 x_batch, 1 context_batch, 2 specialist_ids, 3 emb, 4-11 attn, 12-15 ln,
    // 16-19 ffn, 20 ctxW, 21 ctxb, 22-25 cWq/cWk, 26 cWv, 27 cbv, 28 cWo,
    // 29 cbo, 30 spWp, 31 spbp, 32 spWa, 33 spba
    const float* ctxin = (const float*)d_in[1];
    const int*   sid   = (const int*)d_in[2];
    const float* ctxW  = (const float*)d_in[20];
    const float* ctxb  = (const float*)d_in[21];
    const float* cWv   = (const float*)d_in[26];
    const float* cbv   = (const float*)d_in[27];
    const float* cWo   = (const float*)d_in[28];
    const float* cbo   = (const float*)d_in[29];
    const float* spWp  = (const float*)d_in[30];
    const float* spbp  = (const float*)d_in[31];
    const float* spWa  = (const float*)d_in[32];
    const float* spba  = (const float*)d_in[33];
    float* out = (float*)d_out;
    float* wsP = (float*)d_ws;           // (32,3,512) partials, fully written

    stage_AB<<<dim3(32), dim3(512), 0, stream>>>(
        ctxW, ctxb, cWv, cbv, cWo, wsP);
    stage_heads<<<dim3(64), dim3(256), 0, stream>>>(
        wsP, cbo, spWp, spbp, spWa, spba, ctxin, sid, out);
}

// Round 10
// 152.921 us; speedup vs baseline: 1.0082x; 1.0082x over previous
//
#include <hip/hip_runtime.h>

// Problem: D=512, H=8, L=4, NE=8, B=32, S=512. fp32 in / fp32 out.
//
// Reduction chain (R3-verified absmax 0.0, R4 3.8e-6):
//   cross-attn Sk=1 -> softmax==1 -> last[b] = (ctx[b]@cWv+cbv)@cWo+cbo,
//   ctx[b] = c0[b]*ctxW[0] + c1[b]*ctxW[1] + ctxb  -> batch factors out:
//     A_i = x_i@cWv (x={ctxW0,ctxW1,ctxb}), A2+=cbv
//     B_i = A_i@cWo, B2+=cbo
//     P_i[s,h] = B_i@spW[h][s], P2+=spb
//     out[b,h,o] = c0[b]*P0 + c1[b]*P1 + P2   (s=sid[b])
//
// Final cost model (R3-R9 measured): bench floor ~152us is harness restore +
// 256MB ws re-poison traffic (3x ~42us fills @ 80% HBM peak per iteration);
// our kernels contribute ~5us. All structural alternatives measured and lose
// or tie: coop launch +70 (R5), in-kernel flag barrier +6 (R6), redundant
// compute on few CUs +69 (R7: per-CU BW trap), depth-2 ws-partials +1.8 (R9).
// This is the best-measured variant (R8: 152.4us): 3 small dispatches,
// latency-tuned (GEMV: 512thr/16 indep loads; heads: 64 blocks/32 loads).

#define DD 512

// dst[vec*512+c] = sum_d x_vec[d]*W[d][c] (+bias2 for vec 2)
// grid 32 x 512 thr: block = 16-col slice; thread = (col, 16-row group)
__global__ __launch_bounds__(512) void stage_gemv3(
    const float* __restrict__ x0, const float* __restrict__ x1,
    const float* __restrict__ x2,
    const float* __restrict__ W,      // (512,512) row-major
    const float* __restrict__ bias2,  // (512)
    float*       __restrict__ dst)    // (3,512)
{
    __shared__ float sx[3 * DD];
    __shared__ float red[32][48];     // [dgroup][col*3+vec]
    const int t = threadIdx.x;
    const int cbase = blockIdx.x * 16;

    if (t < DD) {
        sx[t]          = x0[t];
        sx[DD + t]     = x1[t];
        sx[2 * DD + t] = x2[t];
    }
    __syncthreads();

    const int c = t & 15, dg = t >> 4;        // 16 cols x 32 d-groups of 16
    const float* wp = W + (size_t)(dg * 16) * DD + cbase + c;
    float wreg[16];
    #pragma unroll
    for (int j = 0; j < 16; ++j)              // 16 independent loads in flight
        wreg[j] = wp[(size_t)j * DD];
    float p0 = 0.f, p1 = 0.f, p2 = 0.f;
    #pragma unroll
    for (int j = 0; j < 16; ++j) {
        const int d = dg * 16 + j;
        p0 += sx[d] * wreg[j];
        p1 += sx[DD + d] * wreg[j];
        p2 += sx[2 * DD + d] * wreg[j];
    }
    red[dg][c * 3 + 0] = p0;
    red[dg][c * 3 + 1] = p1;
    red[dg][c * 3 + 2] = p2;
    __syncthreads();

    if (t < 48) {                             // 16 cols x 3 vecs
        const int cc = t / 3, vec = t % 3;
        float s = 0.f;
        #pragma unroll
        for (int g = 0; g < 32; ++g) s += red[g][t];
        if (vec == 2) s += bias2[cbase + cc];
        dst[vec * DD + cbase + cc] = s;
    }
}

// heads + batch broadcast. grid 64 (s=blk&7, h=(blk>>3)&1, q=blk>>4) x 256 thr
__global__ __launch_bounds__(256) void stage_heads(
    const float* __restrict__ Bv,     // (3,512)
    const float* __restrict__ spWp, const float* __restrict__ spbp,
    const float* __restrict__ spWa, const float* __restrict__ spba,
    const float* __restrict__ ctxin,  // (32,2)
    const int*   __restrict__ sid,    // (32)
    float*       __restrict__ out)    // pred (32,64) then act (32,64)
{
    __shared__ float sb[3 * DD];
    __shared__ float red[16][48];     // [dgroup][o16*3+vec]
    __shared__ float pv[48];
    __shared__ float sc0[32], sc1[32];
    __shared__ int   ssid[32];
    const int t = threadIdx.x;
    const int s = blockIdx.x & 7, h = (blockIdx.x >> 3) & 1, q = blockIdx.x >> 4;

    for (int i = t; i < 3 * DD; i += 256) sb[i] = Bv[i];
    if (t < 32) {
        ssid[t] = sid[t];
        sc0[t] = ctxin[2 * t];
        sc1[t] = ctxin[2 * t + 1];
    }
    __syncthreads();

    const float* W    = (h ? spWa : spWp) + (size_t)s * DD * 64;
    const float* bias = (h ? spba : spbp) + s * 64;
    const int o16 = t & 15, dg = t >> 4;      // 16 outs x 16 d-groups of 32
    const int o = q * 16 + o16;
    const float* wp = W + (size_t)(dg * 32) * 64 + o;
    float wreg[32];
    #pragma unroll
    for (int j = 0; j < 32; ++j)              // 32 independent loads in flight
        wreg[j] = wp[(size_t)j * 64];
    float p0 = 0.f, p1 = 0.f, p2 = 0.f;
    #pragma unroll
    for (int j = 0; j < 32; ++j) {
        const int d = dg * 32 + j;
        p0 += sb[d] * wreg[j];
        p1 += sb[DD + d] * wreg[j];
        p2 += sb[2 * DD + d] * wreg[j];
    }
    red[dg][o16 * 3 + 0] = p0;
    red[dg][o16 * 3 + 1] = p1;
    red[dg][o16 * 3 + 2] = p2;
    __syncthreads();

    if (t < 48) {
        const int oo = t / 3, vec = t % 3;
        float a = 0.f;
        #pragma unroll
        for (int g = 0; g < 16; ++g) a += red[g][t];
        if (vec == 2) a += bias[q * 16 + oo];
        pv[oo * 3 + vec] = a;
    }
    __syncthreads();

    if (t < 16) {
        const float v0 = pv[t * 3], v1 = pv[t * 3 + 1], v2 = pv[t * 3 + 2];
        #pragma unroll
        for (int b = 0; b < 32; ++b) {
            if (ssid[b] == s) {               // wave-uniform
                out[h * 2048 + b * 64 + q * 16 + t] =
                    sc0[b] * v0 + sc1[b] * v1 + v2;
            }
        }
    }
}

extern "C" void kernel_launch(void* const* d_in, const int* in_sizes, int n_in,
                              void* d_out, int out_size, void* d_ws, size_t ws_size,
                              hipStream_t stream) {
    // 0 x_batch, 1 context_batch, 2 specialist_ids, 3 emb, 4-11 attn, 12-15 ln,
    // 16-19 ffn, 20 ctxW, 21 ctxb, 22-25 cWq/cWk, 26 cWv, 27 cbv, 28 cWo,
    // 29 cbo, 30 spWp, 31 spbp, 32 spWa, 33 spba
    const float* ctxin = (const float*)d_in[1];
    const int*   sid   = (const int*)d_in[2];
    const float* ctxW  = (const float*)d_in[20];
    const float* ctxb  = (const float*)d_in[21];
    const float* cWv   = (const float*)d_in[26];
    const float* cbv   = (const float*)d_in[27];
    const float* cWo   = (const float*)d_in[28];
    const float* cbo   = (const float*)d_in[29];
    const float* spWp  = (const float*)d_in[30];
    const float* spbp  = (const float*)d_in[31];
    const float* spWa  = (const float*)d_in[32];
    const float* spba  = (const float*)d_in[33];
    float* out = (float*)d_out;
    float* wsA = (float*)d_ws;       // A[3][512]
    float* wsB = wsA + 3 * DD;       // B[3][512]

    stage_gemv3<<<dim3(32), dim3(512), 0, stream>>>(
        ctxW, ctxW + DD, ctxb, cWv, cbv, wsA);
    stage_gemv3<<<dim3(32), dim3(512), 0, stream>>>(
        wsA, wsA + DD, wsA + 2 * DD, cWo, cbo, wsB);
    stage_heads<<<dim3(64), dim3(256), 0, stream>>>(
        wsB, spWp, spbp, spWa, spba, ctxin, sid, out);
}